// Round 1
// baseline (905.773 us; speedup 1.0000x reference)
//
#include <hip/hip_runtime.h>
#include <hip/hip_bf16.h>
#include <math.h>

namespace {

constexpr int S  = 2048;
constexpr int D  = 1024;
constexpr int H  = 16;
constexpr int DH = 64;     // head dim
constexpr int QT = 64;     // q rows per block
constexpr int KT = 64;     // k cols per tile
constexpr float SCALE   = 0.125f;   // dh^-0.5 = 64^-0.5
constexpr float EPS_    = 1e-9f;
constexpr float NEG_BIG = -1e9f;

__global__ __launch_bounds__(256, 2)
void euclid_attn_kernel(const float* __restrict__ q,
                        const float* __restrict__ k,
                        const float* __restrict__ v,
                        const int*   __restrict__ mask,
                        float*       __restrict__ out) {
  const int qt = blockIdx.x;       // q-tile index (0..31)
  const int bh = blockIdx.y;       // b*H + h
  const int b  = bh >> 4;          // H == 16
  const int h  = bh & 15;
  const int tid = threadIdx.x;
  const int tx = tid & 15;         // 0..15
  const int ty = tid >> 4;         // 0..15

  // +4 pad keeps float4 alignment and makes all read patterns <=2-way conflicted
  __shared__ float Qs[QT][DH + 4];
  __shared__ float Ks[KT][DH + 4];
  __shared__ float Vs[KT][DH + 4];
  __shared__ float Ps[QT][KT + 4];
  __shared__ float q2s[QT];
  __shared__ float k2s[KT];

  const int q0 = qt * QT;
  const size_t qbase = ((size_t)b * S + q0) * D + h * DH;

  // ---- stage Q tile, fold in per-row |q|^2 via 16-lane shuffle reduce ----
  for (int it = 0; it < 4; ++it) {
    const int r  = ty + 16 * it;
    const int c4 = tx * 4;
    float4 val = *(const float4*)(q + qbase + (size_t)r * D + c4);
    *(float4*)&Qs[r][c4] = val;
    float ss = val.x*val.x + val.y*val.y + val.z*val.z + val.w*val.w;
    ss += __shfl_xor(ss, 1, 16);
    ss += __shfl_xor(ss, 2, 16);
    ss += __shfl_xor(ss, 4, 16);
    ss += __shfl_xor(ss, 8, 16);
    if (tx == 0) q2s[r] = ss;
  }
  __syncthreads();

  float q2r[4];
  for (int i = 0; i < 4; ++i) q2r[i] = q2s[ty + 16 * i];

  float acc[4][4] = {};
  float mreg[4] = {-INFINITY, -INFINITY, -INFINITY, -INFINITY};
  float lreg[4] = {};

  for (int kt = 0; kt < S / KT; ++kt) {
    const int k0 = kt * KT;

    // mask fragment from global (L2/L3 resident); issue early to hide latency
    int mk[4][4];
    for (int i = 0; i < 4; ++i)
      for (int j = 0; j < 4; ++j)
        mk[i][j] = mask[(size_t)(q0 + ty + 16*i) * S + k0 + tx + 16*j];

    __syncthreads();   // prev iteration's PV done with Ks/Vs/Ps

    // ---- stage K and V tiles, fold per-key |k|^2 ----
    const size_t kbase = ((size_t)b * S + k0) * D + h * DH;
    for (int it = 0; it < 4; ++it) {
      const int r  = ty + 16 * it;
      const int c4 = tx * 4;
      float4 kv = *(const float4*)(k + kbase + (size_t)r * D + c4);
      *(float4*)&Ks[r][c4] = kv;
      float ss = kv.x*kv.x + kv.y*kv.y + kv.z*kv.z + kv.w*kv.w;
      ss += __shfl_xor(ss, 1, 16);
      ss += __shfl_xor(ss, 2, 16);
      ss += __shfl_xor(ss, 4, 16);
      ss += __shfl_xor(ss, 8, 16);
      if (tx == 0) k2s[r] = ss;
      float4 vv = *(const float4*)(v + kbase + (size_t)r * D + c4);
      *(float4*)&Vs[r][c4] = vv;
    }
    __syncthreads();

    // ---- QK^T: thread owns rows r_i = ty+16i, cols c_j = tx+16j ----
    float dot[4][4] = {};
    #pragma unroll 4
    for (int kk = 0; kk < DH; kk += 4) {
      float4 qv[4], kv[4];
      for (int i = 0; i < 4; ++i) qv[i] = *(const float4*)&Qs[ty + 16*i][kk];
      for (int j = 0; j < 4; ++j) kv[j] = *(const float4*)&Ks[tx + 16*j][kk];
      for (int i = 0; i < 4; ++i)
        for (int j = 0; j < 4; ++j)
          dot[i][j] += qv[i].x*kv[j].x + qv[i].y*kv[j].y
                     + qv[i].z*kv[j].z + qv[i].w*kv[j].w;
    }

    // ---- scores -> online softmax (all stats in registers, shuffle-broadcast) ----
    float sc[4][4];
    float rmax[4];
    for (int i = 0; i < 4; ++i) {
      float rm = -INFINITY;
      for (int j = 0; j < 4; ++j) {
        float d2   = q2r[i] + k2s[tx + 16*j] - 2.0f * dot[i][j];
        float dist = sqrtf(fmaxf(d2, 0.0f)) * SCALE;
        float a    = 1.0f / (dist + EPS_) + (float)mk[i][j] * NEG_BIG;
        sc[i][j] = a;
        rm = fmaxf(rm, a);
      }
      rm = fmaxf(rm, __shfl_xor(rm, 1, 16));
      rm = fmaxf(rm, __shfl_xor(rm, 2, 16));
      rm = fmaxf(rm, __shfl_xor(rm, 4, 16));
      rm = fmaxf(rm, __shfl_xor(rm, 8, 16));
      rmax[i] = rm;
    }

    for (int i = 0; i < 4; ++i) {
      const float mn   = fmaxf(mreg[i], rmax[i]);
      const float corr = __expf(mreg[i] - mn);   // first tile: exp(-inf)=0
      mreg[i] = mn;
      float rsum = 0.0f;
      float p[4];
      for (int j = 0; j < 4; ++j) {
        p[j] = __expf(sc[i][j] - mn);
        rsum += p[j];
      }
      rsum += __shfl_xor(rsum, 1, 16);
      rsum += __shfl_xor(rsum, 2, 16);
      rsum += __shfl_xor(rsum, 4, 16);
      rsum += __shfl_xor(rsum, 8, 16);
      lreg[i] = lreg[i] * corr + rsum;
      for (int j = 0; j < 4; ++j) {
        acc[i][j] *= corr;
        Ps[ty + 16*i][tx + 16*j] = p[j];
      }
    }
    __syncthreads();

    // ---- PV: acc[i][j] += sum_kk P[r_i][kk] * V[kk][tx*4+j] ----
    #pragma unroll 4
    for (int kk = 0; kk < KT; kk += 4) {
      float4 pv[4];
      for (int i = 0; i < 4; ++i) pv[i] = *(const float4*)&Ps[ty + 16*i][kk];
      const float4 v0 = *(const float4*)&Vs[kk + 0][tx * 4];
      const float4 v1 = *(const float4*)&Vs[kk + 1][tx * 4];
      const float4 v2 = *(const float4*)&Vs[kk + 2][tx * 4];
      const float4 v3 = *(const float4*)&Vs[kk + 3][tx * 4];
      for (int i = 0; i < 4; ++i) {
        acc[i][0] += pv[i].x*v0.x + pv[i].y*v1.x + pv[i].z*v2.x + pv[i].w*v3.x;
        acc[i][1] += pv[i].x*v0.y + pv[i].y*v1.y + pv[i].z*v2.y + pv[i].w*v3.y;
        acc[i][2] += pv[i].x*v0.z + pv[i].y*v1.z + pv[i].z*v2.z + pv[i].w*v3.z;
        acc[i][3] += pv[i].x*v0.w + pv[i].y*v1.w + pv[i].z*v2.w + pv[i].w*v3.w;
      }
    }
  }

  // ---- epilogue: normalize and store (coalesced float4) ----
  for (int i = 0; i < 4; ++i) {
    const float li = 1.0f / lreg[i];
    float4 o;
    o.x = acc[i][0] * li;
    o.y = acc[i][1] * li;
    o.z = acc[i][2] * li;
    o.w = acc[i][3] * li;
    *(float4*)(out + qbase + (size_t)(ty + 16*i) * D + tx * 4) = o;
  }
}

} // namespace

extern "C" void kernel_launch(void* const* d_in, const int* in_sizes, int n_in,
                              void* d_out, int out_size, void* d_ws, size_t ws_size,
                              hipStream_t stream) {
  const float* q    = (const float*)d_in[0];
  const float* k    = (const float*)d_in[1];
  const float* v    = (const float*)d_in[2];
  const int*   mask = (const int*)d_in[3];
  float* out = (float*)d_out;

  const int B = in_sizes[0] / (S * D);   // == 2
  dim3 grid(S / QT, B * H);
  dim3 block(256);
  euclid_attn_kernel<<<grid, block, 0, stream>>>(q, k, v, mask, out);
}

// Round 2
// 455.614 us; speedup vs baseline: 1.9880x; 1.9880x over previous
//
#include <hip/hip_runtime.h>
#include <hip/hip_bf16.h>
#include <math.h>

namespace {

constexpr int S  = 2048;
constexpr int D  = 1024;
constexpr int H  = 16;
constexpr int DH = 64;
constexpr int QB = 32;    // q rows per block (shared by all 4 waves)
constexpr int KT = 64;    // keys per tile
constexpr float NEG_BIG = -1e9f;

typedef __attribute__((ext_vector_type(8))) short short8;
typedef __attribute__((ext_vector_type(4))) float f32x4;

union Frag {
  unsigned u[4];
  short8 v;
};

__device__ __forceinline__ unsigned bf16bits(float f) {
  __hip_bfloat16 h = __float2bfloat16(f);   // RNE
  unsigned short us;
  __builtin_memcpy(&us, &h, 2);
  return (unsigned)us;
}
// pack two floats as bf16 pair: low half = e, high half = o
__device__ __forceinline__ unsigned pk2(float e, float o) {
  return bf16bits(e) | (bf16bits(o) << 16);
}

#define MFMA16 __builtin_amdgcn_mfma_f32_16x16x32_bf16

// Layout conventions (m89-verified D-frag):
//  A-frag: lane holds A[m = lane&15][k-slot (g,j)]   (g = lane>>4, j = 0..7)
//  B-frag: lane holds B[k-slot (g,j)][n = lane&15]
//  D-frag: lane reg r holds D[row = 4*g + r][col = lane&15]
// QK^T swapped: D = mfma(A=K, B=Q) -> S^T[key][q]; lane owns q-col (lane&15),
// keys {16*mf + 4*g + r}. PV: A = P (rebuilt via bpermute), B = V (per-lane
// global column loads).

__global__ __launch_bounds__(256, 2)
void euclid_attn_mfma(const float* __restrict__ qg,
                      const float* __restrict__ kg,
                      const float* __restrict__ vg,
                      const int*   __restrict__ maskg,
                      float*       __restrict__ outg) {
  const int bx = blockIdx.x;           // q-block: rows [32*bx, 32*bx+32)
  const int bh = blockIdx.y;
  const int b  = bh >> 4, h = bh & 15;
  const int tid  = (int)threadIdx.x;
  const int w    = tid >> 6;           // wave 0..3 (k-stripe)
  const int lane = tid & 63;
  const int x    = lane & 15;
  const int g    = lane >> 4;
  const int q0   = bx * QB;

  const float* Qb = qg + ((size_t)b * S + q0) * D + h * DH;
  const float* Kb = kg + (size_t)b * S * D + h * DH;
  const float* Vb = vg + (size_t)b * S * D + h * DH;

  // bpermute byte-indices
  const int idxk0 = (20 * g) * 4;             // +4*r : src lane has x'=4g+r
  const int idxe0 = (32 * (g & 1) + x) * 4;   // +64*bsel : exchange source

  // ---- Q fragments (hi/lo split) + |q|^2, loaded once ----
  Frag Qhi[2][2], Qlo[2][2];     // [nf][s]
  float q2v[2];
#pragma unroll
  for (int nf = 0; nf < 2; ++nf) {
    float ss = 0.f;
#pragma unroll
    for (int s = 0; s < 2; ++s) {
      const float* p = Qb + (16 * nf + x) * D + 32 * s + 8 * g;
      float f[8];
      *(float4*)(f)     = *(const float4*)(p);
      *(float4*)(f + 4) = *(const float4*)(p + 4);
#pragma unroll
      for (int w2 = 0; w2 < 4; ++w2) {
        float e = f[2*w2], o = f[2*w2+1];
        unsigned hw = pk2(e, o);
        Qhi[nf][s].u[w2] = hw;
        float he = __uint_as_float(hw << 16);
        float ho = __uint_as_float(hw & 0xFFFF0000u);
        Qlo[nf][s].u[w2] = pk2(e - he, o - ho);
        ss += e * e + o * o;
      }
    }
    ss += __shfl_xor(ss, 16);
    ss += __shfl_xor(ss, 32);
    q2v[nf] = ss;
  }

  f32x4 acc[2][4] = {};            // [mf_o][nf_v] PV accumulators
  float m_[2] = {-1e30f, -1e30f};  // running max per q-row (per nf)
  float l_[2] = {0.f, 0.f};        // running denom

  const int mrow0 = (q0 + x) * S;

  for (int t = 0; t < (S / KT) / 4; ++t) {
    const int k0 = (w + 4 * t) * KT;

    f32x4 dv[4][2];                // dots -> scores -> p values
    float rmax[2] = {-3e38f, -3e38f};

#pragma unroll
    for (int mf = 0; mf < 4; ++mf) {
      // mask loads for this mf (issued early, used after MFMAs)
      float msk[2][4];
#pragma unroll
      for (int nf = 0; nf < 2; ++nf)
#pragma unroll
        for (int r = 0; r < 4; ++r)
          msk[nf][r] =
              (float)maskg[mrow0 + 16 * nf * S + k0 + 16 * mf + 4 * g + r];

      // K fragment load + hi/lo convert + |k|^2 partial
      const float* kp = Kb + (k0 + 16 * mf + x) * D + 8 * g;
      float f[16];
      *(float4*)(f)      = *(const float4*)(kp);
      *(float4*)(f + 4)  = *(const float4*)(kp + 4);
      *(float4*)(f + 8)  = *(const float4*)(kp + 32);
      *(float4*)(f + 12) = *(const float4*)(kp + 36);
      Frag khi[2], klo[2];
      float ss = 0.f;
#pragma unroll
      for (int s = 0; s < 2; ++s)
#pragma unroll
        for (int w2 = 0; w2 < 4; ++w2) {
          float e = f[8*s + 2*w2], o = f[8*s + 2*w2 + 1];
          unsigned hw = pk2(e, o);
          khi[s].u[w2] = hw;
          float he = __uint_as_float(hw << 16);
          float ho = __uint_as_float(hw & 0xFFFF0000u);
          klo[s].u[w2] = pk2(e - he, o - ho);
          ss += e * e + o * o;
        }
      ss += __shfl_xor(ss, 16);
      ss += __shfl_xor(ss, 32);    // ss = |K[16mf+x]|^2, uniform in g
      float k2r[4];
#pragma unroll
      for (int r = 0; r < 4; ++r)
        k2r[r] = __int_as_float(
            __builtin_amdgcn_ds_bpermute(idxk0 + 4 * r, __float_as_int(ss)));

      // QK^T 3-term split: K_lo*Q_hi + K_hi*Q_lo + K_hi*Q_hi
#pragma unroll
      for (int nf = 0; nf < 2; ++nf) {
        f32x4 d = {0.f, 0.f, 0.f, 0.f};
        d = MFMA16(klo[0].v, Qhi[nf][0].v, d, 0, 0, 0);
        d = MFMA16(khi[0].v, Qlo[nf][0].v, d, 0, 0, 0);
        d = MFMA16(khi[0].v, Qhi[nf][0].v, d, 0, 0, 0);
        d = MFMA16(klo[1].v, Qhi[nf][1].v, d, 0, 0, 0);
        d = MFMA16(khi[1].v, Qlo[nf][1].v, d, 0, 0, 0);
        d = MFMA16(khi[1].v, Qhi[nf][1].v, d, 0, 0, 0);
        dv[mf][nf] = d;
      }

      // scores for this mf: a = 8/sqrt(d2) + mask*NEG_BIG
#pragma unroll
      for (int nf = 0; nf < 2; ++nf)
#pragma unroll
        for (int r = 0; r < 4; ++r) {
          float d2 = q2v[nf] + k2r[r] - 2.f * dv[mf][nf][r];
          d2 = fmaxf(d2, 1e-8f);
          float a = 8.f * rsqrtf(d2);
          a = fmaf(msk[nf][r], NEG_BIG, a);
          dv[mf][nf][r] = a;
          rmax[nf] = fmaxf(rmax[nf], a);
        }
    }

    // ---- online softmax ----
    float corr_s[2];
#pragma unroll
    for (int nf = 0; nf < 2; ++nf) {
      float rm = rmax[nf];
      rm = fmaxf(rm, __shfl_xor(rm, 16));
      rm = fmaxf(rm, __shfl_xor(rm, 32));
      float mn   = fmaxf(m_[nf], rm);
      float corr = __expf(m_[nf] - mn);
      m_[nf] = mn;
      float rs = 0.f;
#pragma unroll
      for (int mf = 0; mf < 4; ++mf)
#pragma unroll
        for (int r = 0; r < 4; ++r) {
          float pp = __expf(dv[mf][nf][r] - mn);
          dv[mf][nf][r] = pp;
          rs += pp;
        }
      rs += __shfl_xor(rs, 16);
      rs += __shfl_xor(rs, 32);
      l_[nf] = l_[nf] * corr + rs;
      corr_s[nf] = corr;
    }

    // rescale acc: corr indexed by acc's q-row (4g+r) via bpermute transpose
#pragma unroll
    for (int mo = 0; mo < 2; ++mo)
#pragma unroll
      for (int r = 0; r < 4; ++r) {
        float cT = __int_as_float(__builtin_amdgcn_ds_bpermute(
            idxk0 + 4 * r, __float_as_int(corr_s[mo])));
#pragma unroll
        for (int nv = 0; nv < 4; ++nv)
          acc[mo][nv][r] *= cT;
      }

    // ---- exchange: P (q-col layout) -> A-frags (q-row layout), hi/lo ----
    unsigned P2h[2][4][2], P2l[2][4][2];   // [nf][mf][c] packed key-pairs
#pragma unroll
    for (int nf = 0; nf < 2; ++nf)
#pragma unroll
      for (int mf = 0; mf < 4; ++mf)
#pragma unroll
        for (int c = 0; c < 2; ++c) {
          float p0 = dv[mf][nf][2*c], p1 = dv[mf][nf][2*c+1];
          unsigned hw = pk2(p0, p1);
          P2h[nf][mf][c] = hw;
          float he = __uint_as_float(hw << 16);
          float ho = __uint_as_float(hw & 0xFFFF0000u);
          P2l[nf][mf][c] = pk2(p0 - he, p1 - ho);
        }

    Frag afh[2][2], afl[2][2];   // [mf_o][s2]
    const bool upper = (g >= 2);
#pragma unroll
    for (int nf = 0; nf < 2; ++nf)
#pragma unroll
      for (int s2 = 0; s2 < 2; ++s2)
#pragma unroll
        for (int w4 = 0; w4 < 4; ++w4) {
          const int c = w4 & 1;
          const int idx = idxe0 + 64 * (w4 >> 1);
          int a0 = __builtin_amdgcn_ds_bpermute(idx, (int)P2h[nf][2*s2][c]);
          int a1 = __builtin_amdgcn_ds_bpermute(idx, (int)P2h[nf][2*s2+1][c]);
          afh[nf][s2].u[w4] = (unsigned)(upper ? a1 : a0);
          int b0 = __builtin_amdgcn_ds_bpermute(idx, (int)P2l[nf][2*s2][c]);
          int b1 = __builtin_amdgcn_ds_bpermute(idx, (int)P2l[nf][2*s2+1][c]);
          afl[nf][s2].u[w4] = (unsigned)(upper ? b1 : b0);
        }

    // ---- PV: per-lane V column loads, 3-term split ----
#pragma unroll
    for (int nv = 0; nv < 4; ++nv)
#pragma unroll
      for (int s2 = 0; s2 < 2; ++s2) {
        const float* vp = Vb + (k0 + 32 * s2 + 8 * g) * D + 16 * nv + x;
        float f[8];
#pragma unroll
        for (int j = 0; j < 8; ++j) f[j] = vp[j * D];
        Frag vh, vl;
#pragma unroll
        for (int w2 = 0; w2 < 4; ++w2) {
          float e = f[2*w2], o = f[2*w2+1];
          unsigned hw = pk2(e, o);
          vh.u[w2] = hw;
          float he = __uint_as_float(hw << 16);
          float ho = __uint_as_float(hw & 0xFFFF0000u);
          vl.u[w2] = pk2(e - he, o - ho);
        }
#pragma unroll
        for (int mo = 0; mo < 2; ++mo) {
          f32x4 a = acc[mo][nv];
          a = MFMA16(afl[mo][s2].v, vh.v, a, 0, 0, 0);
          a = MFMA16(afh[mo][s2].v, vl.v, a, 0, 0, 0);
          a = MFMA16(afh[mo][s2].v, vh.v, a, 0, 0, 0);
          acc[mo][nv] = a;
        }
      }
  }

  // ---- merge the 4 waves' partials (only barrier in the kernel) ----
  __shared__ float accs[4][QB][DH];   // 32 KB
  __shared__ float mls[4][2][QB];     // 1 KB
#pragma unroll
  for (int mo = 0; mo < 2; ++mo)
#pragma unroll
    for (int nv = 0; nv < 4; ++nv)
#pragma unroll
      for (int r = 0; r < 4; ++r)
        accs[w][16 * mo + 4 * g + r][16 * nv + x] = acc[mo][nv][r];
  if (g == 0) {
#pragma unroll
    for (int nf = 0; nf < 2; ++nf) {
      mls[w][0][16 * nf + x] = m_[nf];
      mls[w][1][16 * nf + x] = l_[nf];
    }
  }
  __syncthreads();

  const int qq  = tid >> 3;          // 0..31
  const int dh0 = (tid & 7) * 8;
  float M = -3e38f;
#pragma unroll
  for (int ww = 0; ww < 4; ++ww) M = fmaxf(M, mls[ww][0][qq]);
  float L = 0.f;
  float sw[4];
#pragma unroll
  for (int ww = 0; ww < 4; ++ww) {
    sw[ww] = __expf(mls[ww][0][qq] - M);
    L += sw[ww] * mls[ww][1][qq];
  }
  const float inv = 1.f / L;
  float o[8] = {};
#pragma unroll
  for (int ww = 0; ww < 4; ++ww)
#pragma unroll
    for (int jj = 0; jj < 8; ++jj)
      o[jj] += sw[ww] * accs[ww][qq][dh0 + jj];
#pragma unroll
  for (int jj = 0; jj < 8; ++jj) o[jj] *= inv;
  float* op = outg + ((size_t)b * S + q0 + qq) * D + h * DH + dh0;
  *(float4*)(op)     = *(float4*)(o);
  *(float4*)(op + 4) = *(float4*)(o + 4);
}

} // namespace

extern "C" void kernel_launch(void* const* d_in, const int* in_sizes, int n_in,
                              void* d_out, int out_size, void* d_ws, size_t ws_size,
                              hipStream_t stream) {
  const float* q    = (const float*)d_in[0];
  const float* k    = (const float*)d_in[1];
  const float* v    = (const float*)d_in[2];
  const int*   mask = (const int*)d_in[3];
  float* out = (float*)d_out;

  const int B = in_sizes[0] / (S * D);   // == 2
  dim3 grid(S / QB, B * H);
  dim3 block(256);
  euclid_attn_mfma<<<grid, block, 0, stream>>>(q, k, v, mask, out);
}

// Round 4
// 413.524 us; speedup vs baseline: 2.1904x; 1.1018x over previous
//
#include <hip/hip_runtime.h>
#include <hip/hip_bf16.h>
#include <math.h>

namespace {

constexpr int S  = 2048;
constexpr int D  = 1024;
constexpr int H  = 16;
constexpr int DH = 64;
constexpr int QB = 32;    // q rows per block (shared by all 4 waves)
constexpr int KT = 64;    // keys per tile
constexpr float NEG_BIG = -1e9f;

typedef __attribute__((ext_vector_type(8))) short short8;
typedef __attribute__((ext_vector_type(4))) float f32x4;

union Frag {
  unsigned u[4];
  short8 v;
};

// ---- workspace layout (bytes). bf16 copies: [b][h][s][dh] for K,
// [b][h][dh][s] for V^T; k2 = |k|^2 per (b,h,s).
constexpr size_t ELEMS   = (size_t)2 * H * S * DH;      // 4,194,304 per tensor
constexpr size_t OFF_KHI  = 0;
constexpr size_t OFF_KLO  = ELEMS * 2;
constexpr size_t OFF_VTHI = ELEMS * 4;
constexpr size_t OFF_VTLO = ELEMS * 6;
constexpr size_t OFF_K2   = ELEMS * 8;
constexpr size_t WS_NEED  = ELEMS * 8 + (size_t)2 * H * S * 4;

__device__ __forceinline__ unsigned fbits(float f) { return __float_as_uint(f); }
// pack bf16(lo half from a, hi half from b) by truncation
__device__ __forceinline__ unsigned packhi(unsigned a, unsigned b) {
  return (a >> 16) | (b & 0xFFFF0000u);
}
// truncation hi/lo split of a float pair -> packed bf16x2 hi and lo words
__device__ __forceinline__ void split2(float e, float o, unsigned& hi, unsigned& lo) {
  const unsigned ue = fbits(e), uo = fbits(o);
  hi = packhi(ue, uo);
  const float he = __uint_as_float(ue & 0xFFFF0000u);
  const float ho = __uint_as_float(uo & 0xFFFF0000u);
  lo = packhi(fbits(e - he), fbits(o - ho));
}

// RNE helpers (fallback kernel)
__device__ __forceinline__ unsigned bf16bits(float f) {
  __hip_bfloat16 h = __float2bfloat16(f);
  unsigned short us;
  __builtin_memcpy(&us, &h, 2);
  return (unsigned)us;
}
__device__ __forceinline__ unsigned pk2(float e, float o) {
  return bf16bits(e) | (bf16bits(o) << 16);
}

#define MFMA16 __builtin_amdgcn_mfma_f32_16x16x32_bf16

// ============================ prepass kernels ============================

__global__ __launch_bounds__(256) void prep_k(const float* __restrict__ kin,
                                              short8* __restrict__ khi,
                                              short8* __restrict__ klo,
                                              float* __restrict__ k2) {
  const int t = blockIdx.x * 256 + (int)threadIdx.x;  // 2^19 threads
  const int c = t & 7, h = (t >> 3) & 15, s = (t >> 7) & 2047, b = t >> 18;
  const float* p = kin + ((size_t)(b * S + s)) * D + h * DH + c * 8;
  float f[8];
  *(float4*)f       = *(const float4*)p;
  *(float4*)(f + 4) = *(const float4*)(p + 4);
  Frag hi, lo;
  float ss = 0.f;
#pragma unroll
  for (int w2 = 0; w2 < 4; ++w2) {
    split2(f[2 * w2], f[2 * w2 + 1], hi.u[w2], lo.u[w2]);
    ss += f[2 * w2] * f[2 * w2] + f[2 * w2 + 1] * f[2 * w2 + 1];
  }
  const size_t o8 = ((size_t)((b * 16 + h) * S + s)) * 8 + c;  // DH/8 == 8
  khi[o8] = hi.v;
  klo[o8] = lo.v;
  ss += __shfl_xor(ss, 1, 8);
  ss += __shfl_xor(ss, 2, 8);
  ss += __shfl_xor(ss, 4, 8);
  if (c == 0) k2[(b * 16 + h) * S + s] = ss;
}

__global__ __launch_bounds__(256) void prep_vt(const float* __restrict__ vin,
                                               short8* __restrict__ vthi,
                                               short8* __restrict__ vtlo) {
  __shared__ float Vs[64][65];
  const int blk = blockIdx.x;
  const int st = blk & 31, h = (blk >> 5) & 15, b = blk >> 9;
  const int t = (int)threadIdx.x;
  {
    const int r = t >> 2, cq = t & 3;
    const float* p = vin + ((size_t)(b * S + st * 64 + r)) * D + h * DH + cq * 16;
#pragma unroll
    for (int i = 0; i < 4; ++i)
      *(float4*)&Vs[r][cq * 16 + i * 4] = *(const float4*)(p + i * 4);
  }
  __syncthreads();
  const int d = t >> 2, sq = t & 3;
  Frag h0, h1, l0, l1;
#pragma unroll
  for (int j = 0; j < 4; ++j)
    split2(Vs[sq * 16 + 2 * j][d], Vs[sq * 16 + 2 * j + 1][d], h0.u[j], l0.u[j]);
#pragma unroll
  for (int j = 0; j < 4; ++j)
    split2(Vs[sq * 16 + 8 + 2 * j][d], Vs[sq * 16 + 8 + 2 * j + 1][d], h1.u[j], l1.u[j]);
  const size_t o8 = (((size_t)(b * 16 + h) * DH + d) * S + st * 64 + sq * 16) / 8;
  vthi[o8]     = h0.v;
  vthi[o8 + 1] = h1.v;
  vtlo[o8]     = l0.v;
  vtlo[o8 + 1] = l1.v;
}

// ============================ fast main kernel ============================
// Layouts (m89-verified D-frag): A-frag lane holds A[m=lane&15][k-slot(g,j)],
// B-frag B[k-slot(g,j)][n=lane&15], D-frag reg r = D[4*(lane>>4)+r][lane&15].
// Swapped QK^T: D = mfma(K,Q) -> S^T; lane owns q-col, keys 4g+r.

__global__ __launch_bounds__(256, 2)
void euclid_attn_fast(const float* __restrict__ qg,
                      const int* __restrict__ maskg,
                      const short8* __restrict__ khi,
                      const short8* __restrict__ klo,
                      const short8* __restrict__ vthi,
                      const short8* __restrict__ vtlo,
                      const float* __restrict__ k2g,
                      float* __restrict__ outg) {
  const int bx = blockIdx.x;
  const int bh = blockIdx.y;
  const int b  = bh >> 4;
  const int tid  = (int)threadIdx.x;
  const int w    = tid >> 6;
  const int lane = tid & 63;
  const int x    = lane & 15;
  const int g    = lane >> 4;
  const int q0   = bx * QB;

  const float* Qb = qg + ((size_t)b * S + q0) * D + (bh & 15) * DH;

  const int idxk0 = (20 * g) * 4;
  const int idxe0 = (32 * (g & 1) + x) * 4;

  // ---- Q fragments (trunc hi/lo split) + |q|^2 ----
  Frag Qhi[2][2], Qlo[2][2];
  float q2v[2];
#pragma unroll
  for (int nf = 0; nf < 2; ++nf) {
    float ss = 0.f;
#pragma unroll
    for (int s = 0; s < 2; ++s) {
      const float* p = Qb + (16 * nf + x) * D + 32 * s + 8 * g;
      float f[8];
      *(float4*)(f)     = *(const float4*)(p);
      *(float4*)(f + 4) = *(const float4*)(p + 4);
#pragma unroll
      for (int w2 = 0; w2 < 4; ++w2) {
        split2(f[2 * w2], f[2 * w2 + 1], Qhi[nf][s].u[w2], Qlo[nf][s].u[w2]);
        ss += f[2 * w2] * f[2 * w2] + f[2 * w2 + 1] * f[2 * w2 + 1];
      }
    }
    ss += __shfl_xor(ss, 16);
    ss += __shfl_xor(ss, 32);
    q2v[nf] = ss;
  }

  f32x4 acc[2][4] = {};
  float m_[2] = {-1e30f, -1e30f};
  float l_[2] = {0.f, 0.f};

  const int mrow0 = (q0 + x) * S;

  for (int t = 0; t < (S / KT) / 4; ++t) {
    const int k0 = (w + 4 * t) * KT;

    f32x4 dv[4][2];
    float rmax[2] = {-3e38f, -3e38f};

#pragma unroll
    for (int mf = 0; mf < 4; ++mf) {
      // mask: 4 contiguous keys per lane -> int4
      float mar[2][4];
#pragma unroll
      for (int nf = 0; nf < 2; ++nf) {
        const int4 mi =
            *(const int4*)(maskg + (size_t)mrow0 + 16 * nf * S + k0 + 16 * mf + 4 * g);
        mar[nf][0] = (float)mi.x; mar[nf][1] = (float)mi.y;
        mar[nf][2] = (float)mi.z; mar[nf][3] = (float)mi.w;
      }

      // K fragments: direct bf16 loads from workspace
      const size_t kb8 = ((size_t)bh * S + k0 + 16 * mf + x) * 8;
      Frag kh[2], kl[2];
      kh[0].v = khi[kb8 + g];
      kh[1].v = khi[kb8 + 4 + g];
      kl[0].v = klo[kb8 + g];
      kl[1].v = klo[kb8 + 4 + g];

      const float4 k2r = *(const float4*)(k2g + (size_t)bh * S + k0 + 16 * mf + 4 * g);
      const float k2a[4] = {k2r.x, k2r.y, k2r.z, k2r.w};

#pragma unroll
      for (int nf = 0; nf < 2; ++nf) {
        f32x4 d = {0.f, 0.f, 0.f, 0.f};
        d = MFMA16(kl[0].v, Qhi[nf][0].v, d, 0, 0, 0);
        d = MFMA16(kh[0].v, Qlo[nf][0].v, d, 0, 0, 0);
        d = MFMA16(kh[0].v, Qhi[nf][0].v, d, 0, 0, 0);
        d = MFMA16(kl[1].v, Qhi[nf][1].v, d, 0, 0, 0);
        d = MFMA16(kh[1].v, Qlo[nf][1].v, d, 0, 0, 0);
        d = MFMA16(kh[1].v, Qhi[nf][1].v, d, 0, 0, 0);
        dv[mf][nf] = d;
      }

#pragma unroll
      for (int nf = 0; nf < 2; ++nf)
#pragma unroll
        for (int r = 0; r < 4; ++r) {
          float d2 = q2v[nf] + k2a[r] - 2.f * dv[mf][nf][r];
          d2 = fmaxf(d2, 1e-8f);
          float a = 8.f * rsqrtf(d2);
          a = fmaf(mar[nf][r], NEG_BIG, a);
          dv[mf][nf][r] = a;
          rmax[nf] = fmaxf(rmax[nf], a);
        }
    }

    // ---- online softmax ----
    float corr_s[2];
#pragma unroll
    for (int nf = 0; nf < 2; ++nf) {
      float rm = rmax[nf];
      rm = fmaxf(rm, __shfl_xor(rm, 16));
      rm = fmaxf(rm, __shfl_xor(rm, 32));
      float mn   = fmaxf(m_[nf], rm);
      float corr = __expf(m_[nf] - mn);
      m_[nf] = mn;
      float rs = 0.f;
#pragma unroll
      for (int mf = 0; mf < 4; ++mf)
#pragma unroll
        for (int r = 0; r < 4; ++r) {
          float pp = __expf(dv[mf][nf][r] - mn);
          dv[mf][nf][r] = pp;
          rs += pp;
        }
      rs += __shfl_xor(rs, 16);
      rs += __shfl_xor(rs, 32);
      l_[nf] = l_[nf] * corr + rs;
      corr_s[nf] = corr;
    }

    // rescale acc by corr of the acc's q-row (via bpermute transpose)
#pragma unroll
    for (int mo = 0; mo < 2; ++mo)
#pragma unroll
      for (int r = 0; r < 4; ++r) {
        float cT = __int_as_float(__builtin_amdgcn_ds_bpermute(
            idxk0 + 4 * r, __float_as_int(corr_s[mo])));
#pragma unroll
        for (int nv = 0; nv < 4; ++nv)
          acc[mo][nv][r] *= cT;
      }

    // ---- P trunc-split + exchange to A-frag layout ----
    unsigned P2h[2][4][2], P2l[2][4][2];
#pragma unroll
    for (int nf = 0; nf < 2; ++nf)
#pragma unroll
      for (int mf = 0; mf < 4; ++mf)
#pragma unroll
        for (int c = 0; c < 2; ++c)
          split2(dv[mf][nf][2 * c], dv[mf][nf][2 * c + 1],
                 P2h[nf][mf][c], P2l[nf][mf][c]);

    Frag afh[2][2], afl[2][2];
    const bool upper = (g >= 2);
#pragma unroll
    for (int nf = 0; nf < 2; ++nf)
#pragma unroll
      for (int s2 = 0; s2 < 2; ++s2)
#pragma unroll
        for (int w4 = 0; w4 < 4; ++w4) {
          const int c = w4 & 1;
          const int idx = idxe0 + 64 * (w4 >> 1);
          int a0 = __builtin_amdgcn_ds_bpermute(idx, (int)P2h[nf][2 * s2][c]);
          int a1 = __builtin_amdgcn_ds_bpermute(idx, (int)P2h[nf][2 * s2 + 1][c]);
          afh[nf][s2].u[w4] = (unsigned)(upper ? a1 : a0);
          int b0 = __builtin_amdgcn_ds_bpermute(idx, (int)P2l[nf][2 * s2][c]);
          int b1 = __builtin_amdgcn_ds_bpermute(idx, (int)P2l[nf][2 * s2 + 1][c]);
          afl[nf][s2].u[w4] = (unsigned)(upper ? b1 : b0);
        }

    // ---- PV: V^T bf16 fragment loads ----
#pragma unroll
    for (int nv = 0; nv < 4; ++nv)
#pragma unroll
      for (int s2 = 0; s2 < 2; ++s2) {
        const size_t vt8 =
            (((size_t)bh * DH + 16 * nv + x) * S + k0 + 32 * s2 + 8 * g) / 8;
        Frag vh, vl;
        vh.v = vthi[vt8];
        vl.v = vtlo[vt8];
#pragma unroll
        for (int mo = 0; mo < 2; ++mo) {
          f32x4 a = acc[mo][nv];
          a = MFMA16(afl[mo][s2].v, vh.v, a, 0, 0, 0);
          a = MFMA16(afh[mo][s2].v, vl.v, a, 0, 0, 0);
          a = MFMA16(afh[mo][s2].v, vh.v, a, 0, 0, 0);
          acc[mo][nv] = a;
        }
      }
  }

  // ---- merge 4 waves' partials ----
  __shared__ float accs[4][QB][DH];
  __shared__ float mls[4][2][QB];
#pragma unroll
  for (int mo = 0; mo < 2; ++mo)
#pragma unroll
    for (int nv = 0; nv < 4; ++nv)
#pragma unroll
      for (int r = 0; r < 4; ++r)
        accs[w][16 * mo + 4 * g + r][16 * nv + x] = acc[mo][nv][r];
  if (g == 0) {
#pragma unroll
    for (int nf = 0; nf < 2; ++nf) {
      mls[w][0][16 * nf + x] = m_[nf];
      mls[w][1][16 * nf + x] = l_[nf];
    }
  }
  __syncthreads();

  const int qq  = tid >> 3;
  const int dh0 = (tid & 7) * 8;
  float M = -3e38f;
#pragma unroll
  for (int ww = 0; ww < 4; ++ww) M = fmaxf(M, mls[ww][0][qq]);
  float L = 0.f;
  float sw[4];
#pragma unroll
  for (int ww = 0; ww < 4; ++ww) {
    sw[ww] = __expf(mls[ww][0][qq] - M);
    L += sw[ww] * mls[ww][1][qq];
  }
  const float inv = 1.f / L;
  float o[8] = {};
#pragma unroll
  for (int ww = 0; ww < 4; ++ww)
#pragma unroll
    for (int jj = 0; jj < 8; ++jj)
      o[jj] += sw[ww] * accs[ww][qq][dh0 + jj];
#pragma unroll
  for (int jj = 0; jj < 8; ++jj) o[jj] *= inv;
  float* op = outg + ((size_t)b * S + q0 + qq) * D + (bh & 15) * DH + dh0;
  *(float4*)(op)     = *(float4*)(o);
  *(float4*)(op + 4) = *(float4*)(o + 4);
}

// ==================== fallback (round-2 kernel, verbatim) ====================

__global__ __launch_bounds__(256, 2)
void euclid_attn_mfma(const float* __restrict__ qg,
                      const float* __restrict__ kg,
                      const float* __restrict__ vg,
                      const int*   __restrict__ maskg,
                      float*       __restrict__ outg) {
  const int bx = blockIdx.x;
  const int bh = blockIdx.y;
  const int b  = bh >> 4, h = bh & 15;
  const int tid  = (int)threadIdx.x;
  const int w    = tid >> 6;
  const int lane = tid & 63;
  const int x    = lane & 15;
  const int g    = lane >> 4;
  const int q0   = bx * QB;

  const float* Qb = qg + ((size_t)b * S + q0) * D + h * DH;
  const float* Kb = kg + (size_t)b * S * D + h * DH;
  const float* Vb = vg + (size_t)b * S * D + h * DH;

  const int idxk0 = (20 * g) * 4;
  const int idxe0 = (32 * (g & 1) + x) * 4;

  Frag Qhi[2][2], Qlo[2][2];
  float q2v[2];
#pragma unroll
  for (int nf = 0; nf < 2; ++nf) {
    float ss = 0.f;
#pragma unroll
    for (int s = 0; s < 2; ++s) {
      const float* p = Qb + (16 * nf + x) * D + 32 * s + 8 * g;
      float f[8];
      *(float4*)(f)     = *(const float4*)(p);
      *(float4*)(f + 4) = *(const float4*)(p + 4);
#pragma unroll
      for (int w2 = 0; w2 < 4; ++w2) {
        float e = f[2*w2], o = f[2*w2+1];
        unsigned hw = pk2(e, o);
        Qhi[nf][s].u[w2] = hw;
        float he = __uint_as_float(hw << 16);
        float ho = __uint_as_float(hw & 0xFFFF0000u);
        Qlo[nf][s].u[w2] = pk2(e - he, o - ho);
        ss += e * e + o * o;
      }
    }
    ss += __shfl_xor(ss, 16);
    ss += __shfl_xor(ss, 32);
    q2v[nf] = ss;
  }

  f32x4 acc[2][4] = {};
  float m_[2] = {-1e30f, -1e30f};
  float l_[2] = {0.f, 0.f};

  const int mrow0 = (q0 + x) * S;

  for (int t = 0; t < (S / KT) / 4; ++t) {
    const int k0 = (w + 4 * t) * KT;

    f32x4 dv[4][2];
    float rmax[2] = {-3e38f, -3e38f};

#pragma unroll
    for (int mf = 0; mf < 4; ++mf) {
      float msk[2][4];
#pragma unroll
      for (int nf = 0; nf < 2; ++nf)
#pragma unroll
        for (int r = 0; r < 4; ++r)
          msk[nf][r] =
              (float)maskg[mrow0 + 16 * nf * S + k0 + 16 * mf + 4 * g + r];

      const float* kp = Kb + (k0 + 16 * mf + x) * D + 8 * g;
      float f[16];
      *(float4*)(f)      = *(const float4*)(kp);
      *(float4*)(f + 4)  = *(const float4*)(kp + 4);
      *(float4*)(f + 8)  = *(const float4*)(kp + 32);
      *(float4*)(f + 12) = *(const float4*)(kp + 36);
      Frag khi[2], klo[2];
      float ss = 0.f;
#pragma unroll
      for (int s = 0; s < 2; ++s)
#pragma unroll
        for (int w2 = 0; w2 < 4; ++w2) {
          float e = f[8*s + 2*w2], o = f[8*s + 2*w2 + 1];
          unsigned hw = pk2(e, o);
          khi[s].u[w2] = hw;
          float he = __uint_as_float(hw << 16);
          float ho = __uint_as_float(hw & 0xFFFF0000u);
          klo[s].u[w2] = pk2(e - he, o - ho);
          ss += e * e + o * o;
        }
      ss += __shfl_xor(ss, 16);
      ss += __shfl_xor(ss, 32);
      float k2r[4];
#pragma unroll
      for (int r = 0; r < 4; ++r)
        k2r[r] = __int_as_float(
            __builtin_amdgcn_ds_bpermute(idxk0 + 4 * r, __float_as_int(ss)));

#pragma unroll
      for (int nf = 0; nf < 2; ++nf) {
        f32x4 d = {0.f, 0.f, 0.f, 0.f};
        d = MFMA16(klo[0].v, Qhi[nf][0].v, d, 0, 0, 0);
        d = MFMA16(khi[0].v, Qlo[nf][0].v, d, 0, 0, 0);
        d = MFMA16(khi[0].v, Qhi[nf][0].v, d, 0, 0, 0);
        d = MFMA16(klo[1].v, Qhi[nf][1].v, d, 0, 0, 0);
        d = MFMA16(khi[1].v, Qlo[nf][1].v, d, 0, 0, 0);
        d = MFMA16(khi[1].v, Qhi[nf][1].v, d, 0, 0, 0);
        dv[mf][nf] = d;
      }

#pragma unroll
      for (int nf = 0; nf < 2; ++nf)
#pragma unroll
        for (int r = 0; r < 4; ++r) {
          float d2 = q2v[nf] + k2r[r] - 2.f * dv[mf][nf][r];
          d2 = fmaxf(d2, 1e-8f);
          float a = 8.f * rsqrtf(d2);
          a = fmaf(msk[nf][r], NEG_BIG, a);
          dv[mf][nf][r] = a;
          rmax[nf] = fmaxf(rmax[nf], a);
        }
    }

    float corr_s[2];
#pragma unroll
    for (int nf = 0; nf < 2; ++nf) {
      float rm = rmax[nf];
      rm = fmaxf(rm, __shfl_xor(rm, 16));
      rm = fmaxf(rm, __shfl_xor(rm, 32));
      float mn   = fmaxf(m_[nf], rm);
      float corr = __expf(m_[nf] - mn);
      m_[nf] = mn;
      float rs = 0.f;
#pragma unroll
      for (int mf = 0; mf < 4; ++mf)
#pragma unroll
        for (int r = 0; r < 4; ++r) {
          float pp = __expf(dv[mf][nf][r] - mn);
          dv[mf][nf][r] = pp;
          rs += pp;
        }
      rs += __shfl_xor(rs, 16);
      rs += __shfl_xor(rs, 32);
      l_[nf] = l_[nf] * corr + rs;
      corr_s[nf] = corr;
    }

#pragma unroll
    for (int mo = 0; mo < 2; ++mo)
#pragma unroll
      for (int r = 0; r < 4; ++r) {
        float cT = __int_as_float(__builtin_amdgcn_ds_bpermute(
            idxk0 + 4 * r, __float_as_int(corr_s[mo])));
#pragma unroll
        for (int nv = 0; nv < 4; ++nv)
          acc[mo][nv][r] *= cT;
      }

    unsigned P2h[2][4][2], P2l[2][4][2];
#pragma unroll
    for (int nf = 0; nf < 2; ++nf)
#pragma unroll
      for (int mf = 0; mf < 4; ++mf)
#pragma unroll
        for (int c = 0; c < 2; ++c) {
          float p0 = dv[mf][nf][2*c], p1 = dv[mf][nf][2*c+1];
          unsigned hw = pk2(p0, p1);
          P2h[nf][mf][c] = hw;
          float he = __uint_as_float(hw << 16);
          float ho = __uint_as_float(hw & 0xFFFF0000u);
          P2l[nf][mf][c] = pk2(p0 - he, p1 - ho);
        }

    Frag afh[2][2], afl[2][2];
    const bool upper = (g >= 2);
#pragma unroll
    for (int nf = 0; nf < 2; ++nf)
#pragma unroll
      for (int s2 = 0; s2 < 2; ++s2)
#pragma unroll
        for (int w4 = 0; w4 < 4; ++w4) {
          const int c = w4 & 1;
          const int idx = idxe0 + 64 * (w4 >> 1);
          int a0 = __builtin_amdgcn_ds_bpermute(idx, (int)P2h[nf][2*s2][c]);
          int a1 = __builtin_amdgcn_ds_bpermute(idx, (int)P2h[nf][2*s2+1][c]);
          afh[nf][s2].u[w4] = (unsigned)(upper ? a1 : a0);
          int b0 = __builtin_amdgcn_ds_bpermute(idx, (int)P2l[nf][2*s2][c]);
          int b1 = __builtin_amdgcn_ds_bpermute(idx, (int)P2l[nf][2*s2+1][c]);
          afl[nf][s2].u[w4] = (unsigned)(upper ? b1 : b0);
        }

#pragma unroll
    for (int nv = 0; nv < 4; ++nv)
#pragma unroll
      for (int s2 = 0; s2 < 2; ++s2) {
        const float* vp = Vb + (k0 + 32 * s2 + 8 * g) * D + 16 * nv + x;
        float f[8];
#pragma unroll
        for (int j = 0; j < 8; ++j) f[j] = vp[j * D];
        Frag vh, vl;
#pragma unroll
        for (int w2 = 0; w2 < 4; ++w2) {
          float e = f[2*w2], o = f[2*w2+1];
          unsigned hw = pk2(e, o);
          vh.u[w2] = hw;
          float he = __uint_as_float(hw << 16);
          float ho = __uint_as_float(hw & 0xFFFF0000u);
          vl.u[w2] = pk2(e - he, o - ho);
        }
#pragma unroll
        for (int mo = 0; mo < 2; ++mo) {
          f32x4 a = acc[mo][nv];
          a = MFMA16(afl[mo][s2].v, vh.v, a, 0, 0, 0);
          a = MFMA16(afh[mo][s2].v, vl.v, a, 0, 0, 0);
          a = MFMA16(afh[mo][s2].v, vh.v, a, 0, 0, 0);
          acc[mo][nv] = a;
        }
      }
  }

  __shared__ float accs[4][QB][DH];
  __shared__ float mls[4][2][QB];
#pragma unroll
  for (int mo = 0; mo < 2; ++mo)
#pragma unroll
    for (int nv = 0; nv < 4; ++nv)
#pragma unroll
      for (int r = 0; r < 4; ++r)
        accs[w][16 * mo + 4 * g + r][16 * nv + x] = acc[mo][nv][r];
  if (g == 0) {
#pragma unroll
    for (int nf = 0; nf < 2; ++nf) {
      mls[w][0][16 * nf + x] = m_[nf];
      mls[w][1][16 * nf + x] = l_[nf];
    }
  }
  __syncthreads();

  const int qq  = tid >> 3;
  const int dh0 = (tid & 7) * 8;
  float M = -3e38f;
#pragma unroll
  for (int ww = 0; ww < 4; ++ww) M = fmaxf(M, mls[ww][0][qq]);
  float L = 0.f;
  float sw[4];
#pragma unroll
  for (int ww = 0; ww < 4; ++ww) {
    sw[ww] = __expf(mls[ww][0][qq] - M);
    L += sw[ww] * mls[ww][1][qq];
  }
  const float inv = 1.f / L;
  float o[8] = {};
#pragma unroll
  for (int ww = 0; ww < 4; ++ww)
#pragma unroll
    for (int jj = 0; jj < 8; ++jj)
      o[jj] += sw[ww] * accs[ww][qq][dh0 + jj];
#pragma unroll
  for (int jj = 0; jj < 8; ++jj) o[jj] *= inv;
  float* op = outg + ((size_t)b * S + q0 + qq) * D + h * DH + dh0;
  *(float4*)(op)     = *(float4*)(o);
  *(float4*)(op + 4) = *(float4*)(o + 4);
}

} // namespace

extern "C" void kernel_launch(void* const* d_in, const int* in_sizes, int n_in,
                              void* d_out, int out_size, void* d_ws, size_t ws_size,
                              hipStream_t stream) {
  const float* q    = (const float*)d_in[0];
  const float* k    = (const float*)d_in[1];
  const float* v    = (const float*)d_in[2];
  const int*   mask = (const int*)d_in[3];
  float* out = (float*)d_out;

  const int B = in_sizes[0] / (S * D);   // == 2
  dim3 grid(S / QB, B * H);
  dim3 block(256);

  if (B == 2 && d_ws != nullptr && ws_size >= WS_NEED) {
    char* ws = (char*)d_ws;
    short8* khi  = (short8*)(ws + OFF_KHI);
    short8* klo  = (short8*)(ws + OFF_KLO);
    short8* vthi = (short8*)(ws + OFF_VTHI);
    short8* vtlo = (short8*)(ws + OFF_VTLO);
    float*  k2   = (float*)(ws + OFF_K2);
    prep_k<<<2048, 256, 0, stream>>>(k, khi, klo, k2);
    prep_vt<<<1024, 256, 0, stream>>>(v, vthi, vtlo);
    euclid_attn_fast<<<grid, block, 0, stream>>>(q, mask, khi, klo, vthi, vtlo,
                                                 k2, out);
  } else {
    euclid_attn_mfma<<<grid, block, 0, stream>>>(q, k, v, mask, out);
  }
}